// Round 1
// baseline (635.889 us; speedup 1.0000x reference)
//
#include <hip/hip_runtime.h>
#include <math.h>

#define NN   50000
#define NE   1600000
#define FIN  512
#define H1F  128
#define NCHUNK 49   // ceil(NN/1024)

// ---------------- setup kernels (degree / scan / CSR fill) ----------------

__global__ __launch_bounds__(256) void k_init(int* __restrict__ deg, int* __restrict__ cursor) {
  int i = blockIdx.x * 256 + threadIdx.x;
  if (i < NN) { deg[i] = 0; cursor[i] = 0; }
}

__global__ __launch_bounds__(256) void k_count(const int* __restrict__ ei, int* __restrict__ deg) {
  int e = blockIdx.x * 256 + threadIdx.x;
  if (e < NE) atomicAdd(&deg[ei[NE + e]], 1);
}

__global__ __launch_bounds__(256) void k_partial(const int* __restrict__ deg,
                                                 int* __restrict__ csums,
                                                 float* __restrict__ dinv) {
  __shared__ int red[256];
  int t = threadIdx.x;
  int base = blockIdx.x * 1024 + t * 4;
  int s = 0;
#pragma unroll
  for (int j = 0; j < 4; ++j) {
    int i = base + j;
    if (i < NN) {
      int d = deg[i];
      s += d;
      dinv[i] = rsqrtf((float)(d + 1));   // self-loop included; deg_hat >= 1
    }
  }
  red[t] = s;
  __syncthreads();
  for (int off = 128; off > 0; off >>= 1) {
    if (t < off) red[t] += red[t + off];
    __syncthreads();
  }
  if (t == 0) csums[blockIdx.x] = red[0];
}

__global__ void k_top(int* __restrict__ csums, int* __restrict__ rowptr) {
  if (threadIdx.x == 0 && blockIdx.x == 0) {
    int run = 0;
    for (int c = 0; c < NCHUNK; ++c) { int v = csums[c]; csums[c] = run; run += v; }
    rowptr[NN] = run;   // == NE
  }
}

__global__ __launch_bounds__(256) void k_scan(const int* __restrict__ deg,
                                              const int* __restrict__ csums,
                                              int* __restrict__ rowptr) {
  __shared__ int ts[256];
  int t = threadIdx.x;
  int base = blockIdx.x * 1024 + t * 4;
  int v[4];
  int s = 0;
#pragma unroll
  for (int j = 0; j < 4; ++j) {
    v[j] = (base + j < NN) ? deg[base + j] : 0;
    s += v[j];
  }
  ts[t] = s;
  __syncthreads();
  for (int off = 1; off < 256; off <<= 1) {
    int val = ts[t];
    int add = (t >= off) ? ts[t - off] : 0;
    __syncthreads();
    ts[t] = val + add;
    __syncthreads();
  }
  int excl = (t ? ts[t - 1] : 0) + csums[blockIdx.x];
#pragma unroll
  for (int j = 0; j < 4; ++j) {
    if (base + j < NN) rowptr[base + j] = excl;
    excl += v[j];
  }
}

__global__ __launch_bounds__(256) void k_fill(const int* __restrict__ ei,
                                              const int* __restrict__ rowptr,
                                              int* __restrict__ cursor,
                                              int* __restrict__ csr) {
  int e = blockIdx.x * 256 + threadIdx.x;
  if (e >= NE) return;
  int s = ei[e];
  int d = ei[NE + e];
  int p = atomicAdd(&cursor[d], 1);
  csr[rowptr[d] + p] = s;
}

// ---------------- GEMM1: hw1 = x @ W1  (50000x512 @ 512x128) ----------------
// 64 rows x 128 cols per block, 256 threads, 8x4 micro-tile (cols strided by 32)

__global__ __launch_bounds__(256) void k_gemm1(const float* __restrict__ X,
                                               const float* __restrict__ W,
                                               float* __restrict__ out) {
  __shared__ float As[64][32];
  __shared__ float Bs[32][128];
  int tid  = threadIdx.x;
  int row0 = blockIdx.x * 64;
  int tcol = tid & 31;
  int trow = (tid >> 5) * 8;
  float acc[8][4] = {};
  for (int k0 = 0; k0 < FIN; k0 += 32) {
#pragma unroll
    for (int i = 0; i < 2; ++i) {
      int f = tid + i * 256;
      int r = f >> 3, kq = (f & 7) * 4;
      float4 v = make_float4(0.f, 0.f, 0.f, 0.f);
      if (row0 + r < NN) v = *(const float4*)&X[(size_t)(row0 + r) * FIN + k0 + kq];
      *(float4*)&As[r][kq] = v;
    }
#pragma unroll
    for (int i = 0; i < 4; ++i) {
      int f = tid + i * 256;
      int r = f >> 5, c = (f & 31) * 4;
      *(float4*)&Bs[r][c] = *(const float4*)&W[(size_t)(k0 + r) * H1F + c];
    }
    __syncthreads();
#pragma unroll
    for (int kk = 0; kk < 32; ++kk) {
      float a[8];
#pragma unroll
      for (int r = 0; r < 8; ++r) a[r] = As[trow + r][kk];   // wave-broadcast
      float b0 = Bs[kk][tcol], b1v = Bs[kk][tcol + 32];
      float b2v = Bs[kk][tcol + 64], b3v = Bs[kk][tcol + 96];
#pragma unroll
      for (int r = 0; r < 8; ++r) {
        acc[r][0] += a[r] * b0;  acc[r][1] += a[r] * b1v;
        acc[r][2] += a[r] * b2v; acc[r][3] += a[r] * b3v;
      }
    }
    __syncthreads();
  }
#pragma unroll
  for (int r = 0; r < 8; ++r) {
    int row = row0 + trow + r;
    if (row < NN) {
      size_t base = (size_t)row * H1F;
      out[base + tcol]      = acc[r][0];
      out[base + tcol + 32] = acc[r][1];
      out[base + tcol + 64] = acc[r][2];
      out[base + tcol + 96] = acc[r][3];
    }
  }
}

// ---------------- aggregation: out[d] = dinv[d]*(sum_{s in N(d)} dinv[s]*feat[s] + dinv[d]*feat[d]) (+bias) ----------------
// one wave per dst node, 2 feats per lane (128 feats), coalesced 512B gathers

__global__ __launch_bounds__(256) void k_agg(const float* __restrict__ feat,
                                             const int* __restrict__ rowptr,
                                             const int* __restrict__ csr,
                                             const float* __restrict__ dinv,
                                             const float* __restrict__ bias,
                                             float* __restrict__ out) {
  int gw   = (blockIdx.x * 256 + threadIdx.x) >> 6;   // dst node
  int lane = threadIdx.x & 63;
  if (gw >= NN) return;
  int beg = rowptr[gw], end = rowptr[gw + 1];
  float di = dinv[gw];
  float ax = 0.f, ay = 0.f;
  for (int e = beg; e < end; ++e) {
    int s = csr[e];
    float w = dinv[s];
    float2 v = *(const float2*)&feat[(size_t)s * H1F + lane * 2];
    ax += w * v.x;
    ay += w * v.y;
  }
  float2 vd = *(const float2*)&feat[(size_t)gw * H1F + lane * 2];
  ax = di * (ax + di * vd.x);
  ay = di * (ay + di * vd.y);
  if (bias) { ax += bias[lane * 2]; ay += bias[lane * 2 + 1]; }
  *(float2*)&out[(size_t)gw * H1F + lane * 2] = make_float2(ax, ay);
}

// ---------------- GEMM2 fused: [mu|logvar] = g @ [W2|W3] + [b2|b3]; z = eps*exp(logvar)+mu ----------------

__global__ __launch_bounds__(256) void k_gemm2z(const float* __restrict__ G,
                                                const float* __restrict__ W2,
                                                const float* __restrict__ W3,
                                                const float* __restrict__ b2,
                                                const float* __restrict__ b3,
                                                const float* __restrict__ eps,
                                                float* __restrict__ z) {
  __shared__ float As[64][32];
  __shared__ float Bs[32][128];
  int tid  = threadIdx.x;
  int row0 = blockIdx.x * 64;
  int tcol = tid & 31;
  int trow = (tid >> 5) * 8;
  float acc[8][4] = {};
  for (int k0 = 0; k0 < H1F; k0 += 32) {
#pragma unroll
    for (int i = 0; i < 2; ++i) {
      int f = tid + i * 256;
      int r = f >> 3, kq = (f & 7) * 4;
      float4 v = make_float4(0.f, 0.f, 0.f, 0.f);
      if (row0 + r < NN) v = *(const float4*)&G[(size_t)(row0 + r) * H1F + k0 + kq];
      *(float4*)&As[r][kq] = v;
    }
#pragma unroll
    for (int i = 0; i < 4; ++i) {
      int f = tid + i * 256;
      int r = f >> 5, c = (f & 31) * 4;
      float4 v;
      if (c < 64) v = *(const float4*)&W2[(size_t)(k0 + r) * 64 + c];
      else        v = *(const float4*)&W3[(size_t)(k0 + r) * 64 + (c - 64)];
      *(float4*)&Bs[r][c] = v;
    }
    __syncthreads();
#pragma unroll
    for (int kk = 0; kk < 32; ++kk) {
      float a[8];
#pragma unroll
      for (int r = 0; r < 8; ++r) a[r] = As[trow + r][kk];
      float b0 = Bs[kk][tcol], b1v = Bs[kk][tcol + 32];
      float b2v = Bs[kk][tcol + 64], b3v = Bs[kk][tcol + 96];
#pragma unroll
      for (int r = 0; r < 8; ++r) {
        acc[r][0] += a[r] * b0;  acc[r][1] += a[r] * b1v;
        acc[r][2] += a[r] * b2v; acc[r][3] += a[r] * b3v;
      }
    }
    __syncthreads();
  }
  // cols: tcol -> mu[tcol], tcol+32 -> mu[tcol+32], tcol+64 -> lv[tcol], tcol+96 -> lv[tcol+32]
  float bb2a = b2[tcol], bb2b = b2[tcol + 32];
  float bb3a = b3[tcol], bb3b = b3[tcol + 32];
#pragma unroll
  for (int r = 0; r < 8; ++r) {
    int row = row0 + trow + r;
    if (row < NN) {
      float mu0 = acc[r][0] + bb2a;
      float mu1 = acc[r][1] + bb2b;
      float lv0 = acc[r][2] + bb3a;
      float lv1 = acc[r][3] + bb3b;
      size_t base = (size_t)row * 64;
      z[base + tcol]      = eps[base + tcol]      * __expf(lv0) + mu0;
      z[base + tcol + 32] = eps[base + tcol + 32] * __expf(lv1) + mu1;
    }
  }
}

// ---------------- launch ----------------

extern "C" void kernel_launch(void* const* d_in, const int* in_sizes, int n_in,
                              void* d_out, int out_size, void* d_ws, size_t ws_size,
                              hipStream_t stream) {
  const float* x   = (const float*)d_in[0];
  const int*   ei  = (const int*)  d_in[1];
  const float* W1  = (const float*)d_in[2];
  const float* b1  = (const float*)d_in[3];
  const float* W2  = (const float*)d_in[4];
  const float* b2  = (const float*)d_in[5];
  const float* W3  = (const float*)d_in[6];
  const float* b3  = (const float*)d_in[7];
  const float* eps = (const float*)d_in[8];
  float* z = (float*)d_out;

  char* ws = (char*)d_ws;
  size_t o = 0;
  auto alloc = [&](size_t bytes) -> void* {
    void* p = ws + o;
    o = (o + bytes + 255) & ~(size_t)255;
    return p;
  };
  int*   deg    = (int*)  alloc((size_t)NN * 4);
  int*   rowptr = (int*)  alloc((size_t)(NN + 1) * 4);
  int*   cursor = (int*)  alloc((size_t)NN * 4);
  int*   csums  = (int*)  alloc((size_t)NCHUNK * 4);
  float* dinv   = (float*)alloc((size_t)NN * 4);
  int*   csr    = (int*)  alloc((size_t)NE * 4);
  float* hw1    = (float*)alloc((size_t)NN * H1F * 4);   // also reused as g
  float* h1     = (float*)alloc((size_t)NN * H1F * 4);
  float* g      = hw1;   // hw1 is dead after agg1; reuse

  k_init   <<<(NN + 255) / 256, 256, 0, stream>>>(deg, cursor);
  k_count  <<<(NE + 255) / 256, 256, 0, stream>>>(ei, deg);
  k_partial<<<NCHUNK, 256, 0, stream>>>(deg, csums, dinv);
  k_top    <<<1, 64, 0, stream>>>(csums, rowptr);
  k_scan   <<<NCHUNK, 256, 0, stream>>>(deg, csums, rowptr);
  k_fill   <<<(NE + 255) / 256, 256, 0, stream>>>(ei, rowptr, cursor, csr);

  k_gemm1  <<<(NN + 63) / 64, 256, 0, stream>>>(x, W1, hw1);
  k_agg    <<<(NN + 3) / 4, 256, 0, stream>>>(hw1, rowptr, csr, dinv, b1, h1);   // h1 = Agg(xW1)+b1
  k_agg    <<<(NN + 3) / 4, 256, 0, stream>>>(h1, rowptr, csr, dinv, nullptr, g); // g = Agg(h1)
  k_gemm2z <<<(NN + 63) / 64, 256, 0, stream>>>(g, W2, W3, b2, b3, eps, z);
}

// Round 2
// 445.086 us; speedup vs baseline: 1.4287x; 1.4287x over previous
//
#include <hip/hip_runtime.h>
#include <math.h>

#define NN   50000
#define NE   1600000
#define FIN  512
#define H1F  128
#define NCHUNK 49   // ceil(NN/1024)

// ---------------- bf16 helpers ----------------
__device__ __forceinline__ float bflo(unsigned v) { return __uint_as_float(v << 16); }
__device__ __forceinline__ float bfhi(unsigned v) { return __uint_as_float(v & 0xffff0000u); }
__device__ __forceinline__ unsigned short f2bf(float f) {
  unsigned u = __float_as_uint(f);
  u += 0x7fffu + ((u >> 16) & 1u);   // round-to-nearest-even
  return (unsigned short)(u >> 16);
}
__device__ __forceinline__ unsigned pack2bf(float a, float b) {
  return (unsigned)f2bf(a) | ((unsigned)f2bf(b) << 16);
}

// ---------------- setup kernels (degree / scan / CSR fill) ----------------

__global__ __launch_bounds__(256) void k_init(int* __restrict__ deg, int* __restrict__ cursor) {
  int i = blockIdx.x * 256 + threadIdx.x;
  if (i < NN) { deg[i] = 0; cursor[i] = 0; }
}

__global__ __launch_bounds__(256) void k_count(const int* __restrict__ ei, int* __restrict__ deg) {
  int e = blockIdx.x * 256 + threadIdx.x;
  if (e < NE) atomicAdd(&deg[ei[NE + e]], 1);
}

__global__ __launch_bounds__(256) void k_partial(const int* __restrict__ deg,
                                                 int* __restrict__ csums,
                                                 float* __restrict__ dinv) {
  __shared__ int red[256];
  int t = threadIdx.x;
  int base = blockIdx.x * 1024 + t * 4;
  int s = 0;
#pragma unroll
  for (int j = 0; j < 4; ++j) {
    int i = base + j;
    if (i < NN) {
      int d = deg[i];
      s += d;
      dinv[i] = rsqrtf((float)(d + 1));   // self-loop included; deg_hat >= 1
    }
  }
  red[t] = s;
  __syncthreads();
  for (int off = 128; off > 0; off >>= 1) {
    if (t < off) red[t] += red[t + off];
    __syncthreads();
  }
  if (t == 0) csums[blockIdx.x] = red[0];
}

__global__ void k_top(int* __restrict__ csums, int* __restrict__ rowptr) {
  if (threadIdx.x == 0 && blockIdx.x == 0) {
    int run = 0;
    for (int c = 0; c < NCHUNK; ++c) { int v = csums[c]; csums[c] = run; run += v; }
    rowptr[NN] = run;   // == NE
  }
}

__global__ __launch_bounds__(256) void k_scan(const int* __restrict__ deg,
                                              const int* __restrict__ csums,
                                              int* __restrict__ rowptr) {
  __shared__ int ts[256];
  int t = threadIdx.x;
  int base = blockIdx.x * 1024 + t * 4;
  int v[4];
  int s = 0;
#pragma unroll
  for (int j = 0; j < 4; ++j) {
    v[j] = (base + j < NN) ? deg[base + j] : 0;
    s += v[j];
  }
  ts[t] = s;
  __syncthreads();
  for (int off = 1; off < 256; off <<= 1) {
    int val = ts[t];
    int add = (t >= off) ? ts[t - off] : 0;
    __syncthreads();
    ts[t] = val + add;
    __syncthreads();
  }
  int excl = (t ? ts[t - 1] : 0) + csums[blockIdx.x];
#pragma unroll
  for (int j = 0; j < 4; ++j) {
    if (base + j < NN) rowptr[base + j] = excl;
    excl += v[j];
  }
}

__global__ __launch_bounds__(256) void k_fill(const int* __restrict__ ei,
                                              const int* __restrict__ rowptr,
                                              int* __restrict__ cursor,
                                              int* __restrict__ csr) {
  int e = blockIdx.x * 256 + threadIdx.x;
  if (e >= NE) return;
  int s = ei[e];
  int d = ei[NE + e];
  int p = atomicAdd(&cursor[d], 1);
  csr[rowptr[d] + p] = s;
}

// ---------------- GEMM1: hw1 = bf16(x @ W1)  (50000x512 @ 512x128) ----------------

__global__ __launch_bounds__(256) void k_gemm1(const float* __restrict__ X,
                                               const float* __restrict__ W,
                                               unsigned short* __restrict__ outb) {
  __shared__ float As[64][32];
  __shared__ float Bs[32][128];
  int tid  = threadIdx.x;
  int row0 = blockIdx.x * 64;
  int tcol = tid & 31;
  int trow = (tid >> 5) * 8;
  float acc[8][4] = {};
  for (int k0 = 0; k0 < FIN; k0 += 32) {
#pragma unroll
    for (int i = 0; i < 2; ++i) {
      int f = tid + i * 256;
      int r = f >> 3, kq = (f & 7) * 4;
      float4 v = make_float4(0.f, 0.f, 0.f, 0.f);
      if (row0 + r < NN) v = *(const float4*)&X[(size_t)(row0 + r) * FIN + k0 + kq];
      *(float4*)&As[r][kq] = v;
    }
#pragma unroll
    for (int i = 0; i < 4; ++i) {
      int f = tid + i * 256;
      int r = f >> 5, c = (f & 31) * 4;
      *(float4*)&Bs[r][c] = *(const float4*)&W[(size_t)(k0 + r) * H1F + c];
    }
    __syncthreads();
#pragma unroll
    for (int kk = 0; kk < 32; ++kk) {
      float a[8];
#pragma unroll
      for (int r = 0; r < 8; ++r) a[r] = As[trow + r][kk];
      float b0 = Bs[kk][tcol], b1v = Bs[kk][tcol + 32];
      float b2v = Bs[kk][tcol + 64], b3v = Bs[kk][tcol + 96];
#pragma unroll
      for (int r = 0; r < 8; ++r) {
        acc[r][0] += a[r] * b0;  acc[r][1] += a[r] * b1v;
        acc[r][2] += a[r] * b2v; acc[r][3] += a[r] * b3v;
      }
    }
    __syncthreads();
  }
#pragma unroll
  for (int r = 0; r < 8; ++r) {
    int row = row0 + trow + r;
    if (row < NN) {
      size_t base = (size_t)row * H1F;
      outb[base + tcol]      = f2bf(acc[r][0]);
      outb[base + tcol + 32] = f2bf(acc[r][1]);
      outb[base + tcol + 64] = f2bf(acc[r][2]);
      outb[base + tcol + 96] = f2bf(acc[r][3]);
    }
  }
}

// ---------------- aggregation over bf16 feature table ----------------
// out[d] = dinv[d]*(sum_{s in N(d)} dinv[s]*feat[s] + dinv[d]*feat[d]) (+bias)
// one wave per dst node; 2 feats/lane packed in one uint (256B gather per edge).
// csr indices + dinv loaded coalesced once per 64-edge chunk, broadcast via shfl.

template<bool BIAS, bool OUTBF>
__global__ __launch_bounds__(256) void k_aggb(const unsigned* __restrict__ feat,   // [NN][64] uints
                                              const int* __restrict__ rowptr,
                                              const int* __restrict__ csr,
                                              const float* __restrict__ dinv,
                                              const float* __restrict__ bias,
                                              void* __restrict__ out) {
  int gw   = (blockIdx.x * 256 + threadIdx.x) >> 6;   // dst node
  int lane = threadIdx.x & 63;
  if (gw >= NN) return;
  int beg = rowptr[gw], end = rowptr[gw + 1];
  float di = dinv[gw];
  float ax = 0.f, ay = 0.f;

  for (int e = beg; e < end; e += 64) {
    int cnt = end - e; if (cnt > 64) cnt = 64;
    int sv = 0; float wv = 0.f;
    if (lane < cnt) { sv = csr[e + lane]; wv = dinv[sv]; }
    int j = 0;
    for (; j + 4 <= cnt; j += 4) {
      int s0 = __shfl(sv, j),     s1 = __shfl(sv, j + 1);
      int s2 = __shfl(sv, j + 2), s3 = __shfl(sv, j + 3);
      float w0 = __shfl(wv, j),     w1 = __shfl(wv, j + 1);
      float w2 = __shfl(wv, j + 2), w3 = __shfl(wv, j + 3);
      unsigned v0 = feat[(size_t)s0 * 64 + lane];
      unsigned v1 = feat[(size_t)s1 * 64 + lane];
      unsigned v2 = feat[(size_t)s2 * 64 + lane];
      unsigned v3 = feat[(size_t)s3 * 64 + lane];
      ax += w0 * bflo(v0); ay += w0 * bfhi(v0);
      ax += w1 * bflo(v1); ay += w1 * bfhi(v1);
      ax += w2 * bflo(v2); ay += w2 * bfhi(v2);
      ax += w3 * bflo(v3); ay += w3 * bfhi(v3);
    }
    for (; j < cnt; ++j) {
      int s = __shfl(sv, j);
      float w = __shfl(wv, j);
      unsigned v = feat[(size_t)s * 64 + lane];
      ax += w * bflo(v); ay += w * bfhi(v);
    }
  }
  // self loop
  unsigned vd = feat[(size_t)gw * 64 + lane];
  ax = di * (ax + di * bflo(vd));
  ay = di * (ay + di * bfhi(vd));
  if (BIAS) { ax += bias[lane * 2]; ay += bias[lane * 2 + 1]; }
  if (OUTBF) {
    ((unsigned*)out)[(size_t)gw * 64 + lane] = pack2bf(ax, ay);
  } else {
    ((float2*)out)[(size_t)gw * 64 + lane] = make_float2(ax, ay);
  }
}

// ---------------- GEMM2 fused: [mu|logvar] = g @ [W2|W3] + [b2|b3]; z = eps*exp(logvar)+mu ----------------

__global__ __launch_bounds__(256) void k_gemm2z(const float* __restrict__ G,
                                                const float* __restrict__ W2,
                                                const float* __restrict__ W3,
                                                const float* __restrict__ b2,
                                                const float* __restrict__ b3,
                                                const float* __restrict__ eps,
                                                float* __restrict__ z) {
  __shared__ float As[64][32];
  __shared__ float Bs[32][128];
  int tid  = threadIdx.x;
  int row0 = blockIdx.x * 64;
  int tcol = tid & 31;
  int trow = (tid >> 5) * 8;
  float acc[8][4] = {};
  for (int k0 = 0; k0 < H1F; k0 += 32) {
#pragma unroll
    for (int i = 0; i < 2; ++i) {
      int f = tid + i * 256;
      int r = f >> 3, kq = (f & 7) * 4;
      float4 v = make_float4(0.f, 0.f, 0.f, 0.f);
      if (row0 + r < NN) v = *(const float4*)&G[(size_t)(row0 + r) * H1F + k0 + kq];
      *(float4*)&As[r][kq] = v;
    }
#pragma unroll
    for (int i = 0; i < 4; ++i) {
      int f = tid + i * 256;
      int r = f >> 5, c = (f & 31) * 4;
      float4 v;
      if (c < 64) v = *(const float4*)&W2[(size_t)(k0 + r) * 64 + c];
      else        v = *(const float4*)&W3[(size_t)(k0 + r) * 64 + (c - 64)];
      *(float4*)&Bs[r][c] = v;
    }
    __syncthreads();
#pragma unroll
    for (int kk = 0; kk < 32; ++kk) {
      float a[8];
#pragma unroll
      for (int r = 0; r < 8; ++r) a[r] = As[trow + r][kk];
      float b0 = Bs[kk][tcol], b1v = Bs[kk][tcol + 32];
      float b2v = Bs[kk][tcol + 64], b3v = Bs[kk][tcol + 96];
#pragma unroll
      for (int r = 0; r < 8; ++r) {
        acc[r][0] += a[r] * b0;  acc[r][1] += a[r] * b1v;
        acc[r][2] += a[r] * b2v; acc[r][3] += a[r] * b3v;
      }
    }
    __syncthreads();
  }
  float bb2a = b2[tcol], bb2b = b2[tcol + 32];
  float bb3a = b3[tcol], bb3b = b3[tcol + 32];
#pragma unroll
  for (int r = 0; r < 8; ++r) {
    int row = row0 + trow + r;
    if (row < NN) {
      float mu0 = acc[r][0] + bb2a;
      float mu1 = acc[r][1] + bb2b;
      float lv0 = acc[r][2] + bb3a;
      float lv1 = acc[r][3] + bb3b;
      size_t base = (size_t)row * 64;
      z[base + tcol]      = eps[base + tcol]      * __expf(lv0) + mu0;
      z[base + tcol + 32] = eps[base + tcol + 32] * __expf(lv1) + mu1;
    }
  }
}

// ---------------- launch ----------------

extern "C" void kernel_launch(void* const* d_in, const int* in_sizes, int n_in,
                              void* d_out, int out_size, void* d_ws, size_t ws_size,
                              hipStream_t stream) {
  const float* x   = (const float*)d_in[0];
  const int*   ei  = (const int*)  d_in[1];
  const float* W1  = (const float*)d_in[2];
  const float* b1  = (const float*)d_in[3];
  const float* W2  = (const float*)d_in[4];
  const float* b2  = (const float*)d_in[5];
  const float* W3  = (const float*)d_in[6];
  const float* b3  = (const float*)d_in[7];
  const float* eps = (const float*)d_in[8];
  float* z = (float*)d_out;

  char* ws = (char*)d_ws;
  size_t o = 0;
  auto alloc = [&](size_t bytes) -> void* {
    void* p = ws + o;
    o = (o + bytes + 255) & ~(size_t)255;
    return p;
  };
  int*   deg    = (int*)  alloc((size_t)NN * 4);
  int*   rowptr = (int*)  alloc((size_t)(NN + 1) * 4);
  int*   cursor = (int*)  alloc((size_t)NN * 4);
  int*   csums  = (int*)  alloc((size_t)NCHUNK * 4);
  float* dinv   = (float*)alloc((size_t)NN * 4);
  int*   csr    = (int*)  alloc((size_t)NE * 4);
  unsigned short* hw1b = (unsigned short*)alloc((size_t)NN * H1F * 2);  // bf16 x@W1
  unsigned short* h1b  = (unsigned short*)alloc((size_t)NN * H1F * 2);  // bf16 h1
  float* g = (float*)alloc((size_t)NN * H1F * 4);                       // f32 Agg(h1)

  k_init   <<<(NN + 255) / 256, 256, 0, stream>>>(deg, cursor);
  k_count  <<<(NE + 255) / 256, 256, 0, stream>>>(ei, deg);
  k_partial<<<NCHUNK, 256, 0, stream>>>(deg, csums, dinv);
  k_top    <<<1, 64, 0, stream>>>(csums, rowptr);
  k_scan   <<<NCHUNK, 256, 0, stream>>>(deg, csums, rowptr);
  k_fill   <<<(NE + 255) / 256, 256, 0, stream>>>(ei, rowptr, cursor, csr);

  k_gemm1  <<<(NN + 63) / 64, 256, 0, stream>>>(x, W1, hw1b);
  k_aggb<true,  true ><<<(NN + 3) / 4, 256, 0, stream>>>((const unsigned*)hw1b, rowptr, csr, dinv, b1, (void*)h1b);
  k_aggb<false, false><<<(NN + 3) / 4, 256, 0, stream>>>((const unsigned*)h1b,  rowptr, csr, dinv, nullptr, (void*)g);
  k_gemm2z <<<(NN + 63) / 64, 256, 0, stream>>>(g, W2, W3, b2, b3, eps, z);
}

// Round 3
// 333.339 us; speedup vs baseline: 1.9076x; 1.3352x over previous
//
#include <hip/hip_runtime.h>
#include <math.h>

#define NN   50000
#define NE   1600000
#define FIN  512
#define H1F  128
#define NCHUNK 49   // ceil(NN/1024)

typedef __attribute__((ext_vector_type(8))) short bf16x8;
typedef __attribute__((ext_vector_type(4))) float f32x4;

// ---------------- bf16 helpers ----------------
__device__ __forceinline__ float bflo(unsigned v) { return __uint_as_float(v << 16); }
__device__ __forceinline__ float bfhi(unsigned v) { return __uint_as_float(v & 0xffff0000u); }
__device__ __forceinline__ unsigned short f2bf(float f) {
  unsigned u = __float_as_uint(f);
  u += 0x7fffu + ((u >> 16) & 1u);   // round-to-nearest-even
  return (unsigned short)(u >> 16);
}
__device__ __forceinline__ unsigned pack2bf(float a, float b) {
  return (unsigned)f2bf(a) | ((unsigned)f2bf(b) << 16);
}

// ---------------- setup kernels (degree / scan / CSR fill) ----------------

__global__ __launch_bounds__(256) void k_init(int* __restrict__ deg, int* __restrict__ cursor) {
  int i = blockIdx.x * 256 + threadIdx.x;
  if (i < NN) { deg[i] = 0; cursor[i] = 0; }
}

__global__ __launch_bounds__(256) void k_count(const int* __restrict__ ei, int* __restrict__ deg) {
  int e = blockIdx.x * 256 + threadIdx.x;
  if (e < NE) atomicAdd(&deg[ei[NE + e]], 1);
}

__global__ __launch_bounds__(256) void k_partial(const int* __restrict__ deg,
                                                 int* __restrict__ csums,
                                                 float* __restrict__ dinv) {
  __shared__ int red[256];
  int t = threadIdx.x;
  int base = blockIdx.x * 1024 + t * 4;
  int s = 0;
#pragma unroll
  for (int j = 0; j < 4; ++j) {
    int i = base + j;
    if (i < NN) {
      int d = deg[i];
      s += d;
      dinv[i] = rsqrtf((float)(d + 1));   // self-loop included; deg_hat >= 1
    }
  }
  red[t] = s;
  __syncthreads();
  for (int off = 128; off > 0; off >>= 1) {
    if (t < off) red[t] += red[t + off];
    __syncthreads();
  }
  if (t == 0) csums[blockIdx.x] = red[0];
}

__global__ void k_top(int* __restrict__ csums, int* __restrict__ rowptr) {
  if (threadIdx.x == 0 && blockIdx.x == 0) {
    int run = 0;
    for (int c = 0; c < NCHUNK; ++c) { int v = csums[c]; csums[c] = run; run += v; }
    rowptr[NN] = run;   // == NE
  }
}

__global__ __launch_bounds__(256) void k_scan(const int* __restrict__ deg,
                                              const int* __restrict__ csums,
                                              int* __restrict__ rowptr) {
  __shared__ int ts[256];
  int t = threadIdx.x;
  int base = blockIdx.x * 1024 + t * 4;
  int v[4];
  int s = 0;
#pragma unroll
  for (int j = 0; j < 4; ++j) {
    v[j] = (base + j < NN) ? deg[base + j] : 0;
    s += v[j];
  }
  ts[t] = s;
  __syncthreads();
  for (int off = 1; off < 256; off <<= 1) {
    int val = ts[t];
    int add = (t >= off) ? ts[t - off] : 0;
    __syncthreads();
    ts[t] = val + add;
    __syncthreads();
  }
  int excl = (t ? ts[t - 1] : 0) + csums[blockIdx.x];
#pragma unroll
  for (int j = 0; j < 4; ++j) {
    if (base + j < NN) rowptr[base + j] = excl;
    excl += v[j];
  }
}

__global__ __launch_bounds__(256) void k_fill(const int* __restrict__ ei,
                                              const int* __restrict__ rowptr,
                                              int* __restrict__ cursor,
                                              int* __restrict__ csr) {
  int e = blockIdx.x * 256 + threadIdx.x;
  if (e >= NE) return;
  int s = ei[e];
  int d = ei[NE + e];
  int p = atomicAdd(&cursor[d], 1);
  csr[rowptr[d] + p] = s;
}

// ---------------- W1 -> W1^T bf16  ([512][128] f32 -> [128][512] bf16) ----------------

__global__ __launch_bounds__(256) void k_cvtw1(const float* __restrict__ W,
                                               unsigned short* __restrict__ Wt) {
  int i = blockIdx.x * 256 + threadIdx.x;
  if (i < FIN * H1F) {
    int k = i >> 7, c = i & 127;          // coalesced read of W[k][c]
    Wt[c * FIN + k] = f2bf(W[i]);
  }
}

// ---------------- GEMM1 (MFMA): hw1 = bf16(x @ W1) ----------------
// BM=64 rows x 128 cols per block, 4 waves (wave = 16 rows x 128 cols).
// K staged in 16 steps of 32. A converted f32->bf16 in-register.
// LDS rows padded to 80B (5-word stride) for conflict-free ds_read_b128.
// mfma(Wt_frag, x_frag): lane holds C[row=lane&15][col=f*16+(lane>>4)*4 + 0..3].

#define G1_ABUF 5120          // 64 rows * 80B
#define G1_BBUF 10240         // 128 cols * 80B
#define G1_BUF  (G1_ABUF + G1_BBUF)
#define G1_NSTEP 16

__global__ __launch_bounds__(256) void k_gemm1m(const float* __restrict__ X,
                                                const unsigned short* __restrict__ W1t,
                                                unsigned short* __restrict__ outb) {
  __shared__ char lds[2 * G1_BUF];
  int tid  = threadIdx.x;
  int row0 = blockIdx.x * 64;
  int w    = tid >> 6;
  int lane = tid & 63;

  // staging roles
  int ar = tid >> 2, aq = tid & 3;        // A: row ar, k-chunk aq (8 floats)
  int bc = tid >> 1, bh = tid & 1;        // B: col bc, half bh (16 bf16)

  float4 av0, av1;
  uint4  bu0, bu1;

  auto load_g = [&](int s) {
    int k0 = s * 32;
    int row = row0 + ar;
    av0 = make_float4(0.f, 0.f, 0.f, 0.f);
    av1 = av0;
    if (row < NN) {
      const float* gp = X + (size_t)row * FIN + k0 + aq * 8;
      av0 = *(const float4*)gp;
      av1 = *(const float4*)(gp + 4);
    }
    const uint4* bp = (const uint4*)(W1t + (size_t)bc * FIN + k0 + bh * 16);
    bu0 = bp[0];
    bu1 = bp[1];
  };
  auto store_l = [&](int buf) {
    char* Ab = lds + buf * G1_BUF;
    char* Bb = Ab + G1_ABUF;
    uint4 ap;
    ap.x = pack2bf(av0.x, av0.y); ap.y = pack2bf(av0.z, av0.w);
    ap.z = pack2bf(av1.x, av1.y); ap.w = pack2bf(av1.z, av1.w);
    *(uint4*)(Ab + ar * 80 + aq * 16) = ap;
    *(uint4*)(Bb + bc * 80 + bh * 32)      = bu0;
    *(uint4*)(Bb + bc * 80 + bh * 32 + 16) = bu1;
  };

  f32x4 acc[8];
#pragma unroll
  for (int f = 0; f < 8; ++f) acc[f] = (f32x4){0.f, 0.f, 0.f, 0.f};

  load_g(0);
  store_l(0);

  for (int s = 0; s < G1_NSTEP; ++s) {
    if (s + 1 < G1_NSTEP) load_g(s + 1);      // overlap HBM latency with MFMA
    __syncthreads();                           // buf[s&1] writes complete
    const char* Ab = lds + (s & 1) * G1_BUF;
    const char* Bb = Ab + G1_ABUF;
    bf16x8 xa = *(const bf16x8*)(Ab + (w * 16 + (lane & 15)) * 80 + (lane >> 4) * 16);
#pragma unroll
    for (int f = 0; f < 8; ++f) {
      bf16x8 bt = *(const bf16x8*)(Bb + (f * 16 + (lane & 15)) * 80 + (lane >> 4) * 16);
      acc[f] = __builtin_amdgcn_mfma_f32_16x16x32_bf16(bt, xa, acc[f], 0, 0, 0);
    }
    if (s + 1 < G1_NSTEP) store_l((s + 1) & 1);  // write-late into other buffer
  }

  int orow = row0 + w * 16 + (lane & 15);
  if (orow < NN) {
    size_t base = (size_t)orow * H1F;
#pragma unroll
    for (int f = 0; f < 8; ++f) {
      int col = f * 16 + (lane >> 4) * 4;
      uint2 pk;
      pk.x = pack2bf(acc[f][0], acc[f][1]);
      pk.y = pack2bf(acc[f][2], acc[f][3]);
      *(uint2*)(outb + base + col) = pk;       // 8B store, 8B-aligned
    }
  }
}

// ---------------- aggregation over bf16 feature table ----------------
// out[d] = dinv[d]*(sum_{s in N(d)} dinv[s]*feat[s] + dinv[d]*feat[d]) (+bias)
// one wave per dst node; 2 feats/lane packed in one uint (256B gather per edge).

template<bool BIAS, bool OUTBF>
__global__ __launch_bounds__(256) void k_aggb(const unsigned* __restrict__ feat,   // [NN][64] uints
                                              const int* __restrict__ rowptr,
                                              const int* __restrict__ csr,
                                              const float* __restrict__ dinv,
                                              const float* __restrict__ bias,
                                              void* __restrict__ out) {
  int gw   = (blockIdx.x * 256 + threadIdx.x) >> 6;   // dst node
  int lane = threadIdx.x & 63;
  if (gw >= NN) return;
  int beg = rowptr[gw], end = rowptr[gw + 1];
  float di = dinv[gw];
  float ax = 0.f, ay = 0.f;

  for (int e = beg; e < end; e += 64) {
    int cnt = end - e; if (cnt > 64) cnt = 64;
    int sv = 0; float wv = 0.f;
    if (lane < cnt) { sv = csr[e + lane]; wv = dinv[sv]; }
    int j = 0;
    for (; j + 4 <= cnt; j += 4) {
      int s0 = __shfl(sv, j),     s1 = __shfl(sv, j + 1);
      int s2 = __shfl(sv, j + 2), s3 = __shfl(sv, j + 3);
      float w0 = __shfl(wv, j),     w1 = __shfl(wv, j + 1);
      float w2 = __shfl(wv, j + 2), w3 = __shfl(wv, j + 3);
      unsigned v0 = feat[(size_t)s0 * 64 + lane];
      unsigned v1 = feat[(size_t)s1 * 64 + lane];
      unsigned v2 = feat[(size_t)s2 * 64 + lane];
      unsigned v3 = feat[(size_t)s3 * 64 + lane];
      ax += w0 * bflo(v0); ay += w0 * bfhi(v0);
      ax += w1 * bflo(v1); ay += w1 * bfhi(v1);
      ax += w2 * bflo(v2); ay += w2 * bfhi(v2);
      ax += w3 * bflo(v3); ay += w3 * bfhi(v3);
    }
    for (; j < cnt; ++j) {
      int s = __shfl(sv, j);
      float w = __shfl(wv, j);
      unsigned v = feat[(size_t)s * 64 + lane];
      ax += w * bflo(v); ay += w * bfhi(v);
    }
  }
  // self loop
  unsigned vd = feat[(size_t)gw * 64 + lane];
  ax = di * (ax + di * bflo(vd));
  ay = di * (ay + di * bfhi(vd));
  if (BIAS) { ax += bias[lane * 2]; ay += bias[lane * 2 + 1]; }
  if (OUTBF) {
    ((unsigned*)out)[(size_t)gw * 64 + lane] = pack2bf(ax, ay);
  } else {
    ((float2*)out)[(size_t)gw * 64 + lane] = make_float2(ax, ay);
  }
}

// ---------------- GEMM2 fused: [mu|logvar] = g @ [W2|W3] + [b2|b3]; z = eps*exp(logvar)+mu ----------------

__global__ __launch_bounds__(256) void k_gemm2z(const float* __restrict__ G,
                                                const float* __restrict__ W2,
                                                const float* __restrict__ W3,
                                                const float* __restrict__ b2,
                                                const float* __restrict__ b3,
                                                const float* __restrict__ eps,
                                                float* __restrict__ z) {
  __shared__ float As[64][32];
  __shared__ float Bs[32][128];
  int tid  = threadIdx.x;
  int row0 = blockIdx.x * 64;
  int tcol = tid & 31;
  int trow = (tid >> 5) * 8;
  float acc[8][4] = {};
  for (int k0 = 0; k0 < H1F; k0 += 32) {
#pragma unroll
    for (int i = 0; i < 2; ++i) {
      int f = tid + i * 256;
      int r = f >> 3, kq = (f & 7) * 4;
      float4 v = make_float4(0.f, 0.f, 0.f, 0.f);
      if (row0 + r < NN) v = *(const float4*)&G[(size_t)(row0 + r) * H1F + k0 + kq];
      *(float4*)&As[r][kq] = v;
    }
#pragma unroll
    for (int i = 0; i < 4; ++i) {
      int f = tid + i * 256;
      int r = f >> 5, c = (f & 31) * 4;
      float4 v;
      if (c < 64) v = *(const float4*)&W2[(size_t)(k0 + r) * 64 + c];
      else        v = *(const float4*)&W3[(size_t)(k0 + r) * 64 + (c - 64)];
      *(float4*)&Bs[r][c] = v;
    }
    __syncthreads();
#pragma unroll
    for (int kk = 0; kk < 32; ++kk) {
      float a[8];
#pragma unroll
      for (int r = 0; r < 8; ++r) a[r] = As[trow + r][kk];
      float b0 = Bs[kk][tcol], b1v = Bs[kk][tcol + 32];
      float b2v = Bs[kk][tcol + 64], b3v = Bs[kk][tcol + 96];
#pragma unroll
      for (int r = 0; r < 8; ++r) {
        acc[r][0] += a[r] * b0;  acc[r][1] += a[r] * b1v;
        acc[r][2] += a[r] * b2v; acc[r][3] += a[r] * b3v;
      }
    }
    __syncthreads();
  }
  float bb2a = b2[tcol], bb2b = b2[tcol + 32];
  float bb3a = b3[tcol], bb3b = b3[tcol + 32];
#pragma unroll
  for (int r = 0; r < 8; ++r) {
    int row = row0 + trow + r;
    if (row < NN) {
      float mu0 = acc[r][0] + bb2a;
      float mu1 = acc[r][1] + bb2b;
      float lv0 = acc[r][2] + bb3a;
      float lv1 = acc[r][3] + bb3b;
      size_t base = (size_t)row * 64;
      z[base + tcol]      = eps[base + tcol]      * __expf(lv0) + mu0;
      z[base + tcol + 32] = eps[base + tcol + 32] * __expf(lv1) + mu1;
    }
  }
}

// ---------------- launch ----------------

extern "C" void kernel_launch(void* const* d_in, const int* in_sizes, int n_in,
                              void* d_out, int out_size, void* d_ws, size_t ws_size,
                              hipStream_t stream) {
  const float* x   = (const float*)d_in[0];
  const int*   ei  = (const int*)  d_in[1];
  const float* W1  = (const float*)d_in[2];
  const float* b1  = (const float*)d_in[3];
  const float* W2  = (const float*)d_in[4];
  const float* b2  = (const float*)d_in[5];
  const float* W3  = (const float*)d_in[6];
  const float* b3  = (const float*)d_in[7];
  const float* eps = (const float*)d_in[8];
  float* z = (float*)d_out;

  char* ws = (char*)d_ws;
  size_t o = 0;
  auto alloc = [&](size_t bytes) -> void* {
    void* p = ws + o;
    o = (o + bytes + 255) & ~(size_t)255;
    return p;
  };
  int*   deg    = (int*)  alloc((size_t)NN * 4);
  int*   rowptr = (int*)  alloc((size_t)(NN + 1) * 4);
  int*   cursor = (int*)  alloc((size_t)NN * 4);
  int*   csums  = (int*)  alloc((size_t)NCHUNK * 4);
  float* dinv   = (float*)alloc((size_t)NN * 4);
  int*   csr    = (int*)  alloc((size_t)NE * 4);
  unsigned short* W1t  = (unsigned short*)alloc((size_t)H1F * FIN * 2);  // bf16 W1^T
  unsigned short* hw1b = (unsigned short*)alloc((size_t)NN * H1F * 2);   // bf16 x@W1
  unsigned short* h1b  = (unsigned short*)alloc((size_t)NN * H1F * 2);   // bf16 h1
  float* g = (float*)alloc((size_t)NN * H1F * 4);                        // f32 Agg(h1)

  k_init   <<<(NN + 255) / 256, 256, 0, stream>>>(deg, cursor);
  k_count  <<<(NE + 255) / 256, 256, 0, stream>>>(ei, deg);
  k_partial<<<NCHUNK, 256, 0, stream>>>(deg, csums, dinv);
  k_top    <<<1, 64, 0, stream>>>(csums, rowptr);
  k_scan   <<<NCHUNK, 256, 0, stream>>>(deg, csums, rowptr);
  k_fill   <<<(NE + 255) / 256, 256, 0, stream>>>(ei, rowptr, cursor, csr);
  k_cvtw1  <<<(FIN * H1F + 255) / 256, 256, 0, stream>>>(W1, W1t);

  k_gemm1m <<<(NN + 63) / 64, 256, 0, stream>>>(x, W1t, hw1b);
  k_aggb<true,  true ><<<(NN + 3) / 4, 256, 0, stream>>>((const unsigned*)hw1b, rowptr, csr, dinv, b1, (void*)h1b);
  k_aggb<false, false><<<(NN + 3) / 4, 256, 0, stream>>>((const unsigned*)h1b,  rowptr, csr, dinv, nullptr, (void*)g);
  k_gemm2z <<<(NN + 63) / 64, 256, 0, stream>>>(g, W2, W3, b2, b3, eps, z);
}